// Round 7
// baseline (201.671 us; speedup 1.0000x reference)
//
#include <hip/hip_runtime.h>
#include <hip/hip_bf16.h>
#include <math.h>

typedef __attribute__((ext_vector_type(8))) __bf16 bf16x8;
typedef __attribute__((ext_vector_type(4))) float f32x4;

__device__ __forceinline__ float sigmoid_f(float v) {
  return __builtin_amdgcn_rcpf(1.f + __expf(-v));
}
__device__ __forceinline__ float tanh_f(float z) {
  float az = fabsf(z);
  float e = __expf(-2.f * az);
  float t = (1.f - e) * __builtin_amdgcn_rcpf(1.f + e);
  return copysignf(t, z);
}
__device__ __forceinline__ bf16x8 cvt8(float4 a, float4 b) {
  bf16x8 r;
  r[0] = (__bf16)a.x; r[1] = (__bf16)a.y; r[2] = (__bf16)a.z; r[3] = (__bf16)a.w;
  r[4] = (__bf16)b.x; r[5] = (__bf16)b.y; r[6] = (__bf16)b.z; r[7] = (__bf16)b.w;
  return r;
}

// Pack W_x/W_h fp32 -> bf16 into 12 half-matrix blocks of 16KB, index (ch*6+m).
// m-order: 0 Wx_r, 1 Wx_h, 2 Wh_r, 3 Wh_h, 4 Wx_u, 5 Wh_u.
// One col-half (6 half-matrices, 96KB) is contiguous at wp + ch*49152.
// 16B chunk c2 = (nt*4+kt)*64 + lane holds
//   W[ro + ch*64 + nt*16 + (lane&15)][kt*32 + (lane>>4)*8 .. +7].
// global_load_lds staging (wave-uniform base + lane*16) lands exactly where the
// ds_read_b128 B-frag reads expect it: both wave-linear, 0 bank conflicts.
__global__ void pack_weights_kernel(const float* __restrict__ Wx,
                                    const float* __restrict__ Wh,
                                    unsigned short* __restrict__ wp) {
  int t = blockIdx.x * 256 + threadIdx.x;
  if (t >= 12288) return;          // 2 halves * 6 matrices * 1024 chunks
  int ch = t / 6144;
  int r  = t - ch * 6144;
  int m  = r >> 10;
  int c2 = r & 1023;
  int nt = c2 >> 8;
  int kt = (c2 >> 6) & 3;
  int lane = c2 & 63;
  const float* src; int ro;
  switch (m) {
    case 0: src = Wx; ro = 128; break;   // Wx_r
    case 1: src = Wx; ro = 256; break;   // Wx_h
    case 2: src = Wh; ro = 128; break;   // Wh_r
    case 3: src = Wh; ro = 256; break;   // Wh_h
    case 4: src = Wx; ro = 0;   break;   // Wx_u
    default: src = Wh; ro = 0;  break;   // Wh_u
  }
  const float* p = src + (ro + ch * 64 + nt * 16 + (lane & 15)) * 128
                       + kt * 32 + (lane >> 4) * 8;
  *(bf16x8*)(wp + t * 8) = cvt8(*(const float4*)p, *(const float4*)(p + 4));
}

// 256 threads = 4 waves, 96KB LDS -> 1 block/CU, 256 blocks = whole grid
// resident in one shot. Per col-half: stage all 6 half-matrices ONCE, then
// 4 row-chunks of 64 rows with ZERO fences (weights resident; x/h loaded
// just-in-time as transients -> no spill). 3 barriers per block total.
__global__ __launch_bounds__(256, 1) void augru_kernel(
    const float* __restrict__ x, const float* __restrict__ hp,
    const float* __restrict__ att, const unsigned short* __restrict__ wp,
    const float* __restrict__ bx, const float* __restrict__ bh,
    float* __restrict__ out) {
  extern __shared__ unsigned short wlds[];  // 96 KB = 49152 shorts
  const int tid  = threadIdx.x;
  const int wave = tid >> 6;
  const int lane = tid & 63;
  const int quad = lane >> 4;
  const int l15  = lane & 15;
  const int row0 = blockIdx.x * 256;  // block's 256 rows

  // stage one col-half's 96KB: 24 rounds x 256 threads x 16B, wave-linear
  auto stage = [&](int ch) {
#pragma unroll
    for (int i = 0; i < 24; ++i) {
      const unsigned short* g = wp + ch * 49152 + (i * 256 + tid) * 8;
      unsigned short* l = &wlds[(i * 256 + wave * 64) * 8];  // HW adds lane*16B
      __builtin_amdgcn_global_load_lds(
          (const __attribute__((address_space(1))) void*)g,
          (__attribute__((address_space(3))) void*)l, 16, 0, 0);
    }
  };

  // one half-matrix gemm: 16 ds_read_b128 + 16 MFMA, wave-linear (0 conflicts)
  auto gemm = [&](int m, const bf16x8 (&af)[4], f32x4 (&acc)[4]) {
#pragma unroll
    for (int nt = 0; nt < 4; ++nt)
#pragma unroll
      for (int kt = 0; kt < 4; ++kt) {
        bf16x8 bfrag = *(const bf16x8*)&wlds[m * 8192 + ((nt * 4 + kt) * 64 + lane) * 8];
        acc[nt] = __builtin_amdgcn_mfma_f32_16x16x32_bf16(af[kt], bfrag, acc[nt], 0, 0, 0);
      }
  };

  stage(0);
  asm volatile("s_waitcnt vmcnt(0)" ::: "memory");
  __syncthreads();  // col-half-0 weights resident

#pragma unroll 1
  for (int ch = 0; ch < 2; ++ch) {
    const int cb = ch * 64;  // column base
    float br[4], bhh[4], bxh[4], bu[4];
#pragma unroll
    for (int nt = 0; nt < 4; ++nt) {
      int col = cb + nt * 16 + l15;
      br[nt]  = bx[128 + col] + bh[128 + col];
      bhh[nt] = bh[256 + col];
      bxh[nt] = bx[256 + col];
      bu[nt]  = bx[col] + bh[col];
    }

#pragma unroll 1
    for (int c = 0; c < 4; ++c) {
      const int rbase = row0 + c * 64 + wave * 16;  // this wave's 16 rows

      // just-in-time A-frags: transient float4s, dead after conversion
      bf16x8 xf[4], hf[4];
      {
        const float* xr = x  + (rbase + l15) * 128;
        const float* hr = hp + (rbase + l15) * 128;
        float4 xa[8], ha[8];
#pragma unroll
        for (int kt = 0; kt < 4; ++kt) {
          int off = kt * 32 + quad * 8;
          xa[2 * kt]     = *(const float4*)(xr + off);
          xa[2 * kt + 1] = *(const float4*)(xr + off + 4);
          ha[2 * kt]     = *(const float4*)(hr + off);
          ha[2 * kt + 1] = *(const float4*)(hr + off + 4);
        }
#pragma unroll
        for (int kt = 0; kt < 4; ++kt) {
          xf[kt] = cvt8(xa[2 * kt], xa[2 * kt + 1]);
          hf[kt] = cvt8(ha[2 * kt], ha[2 * kt + 1]);
        }
      }
      float atts[4];
#pragma unroll
      for (int r = 0; r < 4; ++r) atts[r] = att[rbase + quad * 4 + r];

      f32x4 accR[4], accH[4], keep[4];
#pragma unroll
      for (int nt = 0; nt < 4; ++nt) { accR[nt] = (f32x4)0.f; accH[nt] = (f32x4)0.f; }

      gemm(0, xf, accR);   // x . Wx_r
      gemm(1, xf, accH);   // x . Wx_h
      gemm(2, hf, accR);   // + h . Wh_r
#pragma unroll
      for (int nt = 0; nt < 4; ++nt)
#pragma unroll
        for (int r = 0; r < 4; ++r) {
          keep[nt][r] = sigmoid_f(accR[nt][r] + br[nt]);   // r-gate
          accR[nt][r] = 0.f;
        }
      gemm(3, hf, accR);   // h . Wh_h
#pragma unroll
      for (int nt = 0; nt < 4; ++nt)
#pragma unroll
        for (int r = 0; r < 4; ++r) {
          // h_tilde = tanh(x.Wx_h + bx_h + r * (h.Wh_h + bh_h))
          keep[nt][r] = tanh_f(accH[nt][r] + bxh[nt] + keep[nt][r] * (accR[nt][r] + bhh[nt]));
          accR[nt][r] = 0.f;
        }
      // prefetch exact-fp32 h_prev for the blend; lands under the u-gemms
      float h0[4][4];
#pragma unroll
      for (int nt = 0; nt < 4; ++nt)
#pragma unroll
        for (int r = 0; r < 4; ++r)
          h0[nt][r] = hp[(rbase + quad * 4 + r) * 128 + cb + nt * 16 + l15];

      gemm(4, xf, accR);   // x . Wx_u
      gemm(5, hf, accR);   // + h . Wh_u
#pragma unroll
      for (int nt = 0; nt < 4; ++nt) {
        int col = cb + nt * 16 + l15;
#pragma unroll
        for (int r = 0; r < 4; ++r) {
          int row = rbase + quad * 4 + r;
          float u  = sigmoid_f(accR[nt][r] + bu[nt]);
          float ua = atts[r] * u;
          out[row * 128 + col] = fmaf(ua, keep[nt][r] - h0[nt][r], h0[nt][r]);
        }
      }
    }

    if (ch == 0) {
      __syncthreads();   // all waves done reading half-0 weights
      stage(1);
      asm volatile("s_waitcnt vmcnt(0)" ::: "memory");
      __syncthreads();   // col-half-1 weights resident
    }
  }
}

extern "C" void kernel_launch(void* const* d_in, const int* in_sizes, int n_in,
                              void* d_out, int out_size, void* d_ws, size_t ws_size,
                              hipStream_t stream) {
  const float* x   = (const float*)d_in[0];
  const float* hpv = (const float*)d_in[1];
  const float* att = (const float*)d_in[2];
  const float* Wx  = (const float*)d_in[3];
  const float* bx  = (const float*)d_in[4];
  const float* Wh  = (const float*)d_in[5];
  const float* bh  = (const float*)d_in[6];
  float* out = (float*)d_out;
  unsigned short* wp = (unsigned short*)d_ws;  // 196,608 B of scratch

  pack_weights_kernel<<<48, 256, 0, stream>>>(Wx, Wh, wp);
  augru_kernel<<<256, 256, 98304, stream>>>(x, hpv, att, wp, bx, bh, out);
}

// Round 8
// 142.320 us; speedup vs baseline: 1.4170x; 1.4170x over previous
//
#include <hip/hip_runtime.h>
#include <hip/hip_bf16.h>
#include <math.h>

typedef __attribute__((ext_vector_type(8))) __bf16 bf16x8;
typedef __attribute__((ext_vector_type(16))) float f32x16;

__device__ __forceinline__ float sigmoid_f(float v) {
  return __builtin_amdgcn_rcpf(1.f + __expf(-v));
}
__device__ __forceinline__ float tanh_f(float z) {
  float az = fabsf(z);
  float e = __expf(-2.f * az);
  float t = (1.f - e) * __builtin_amdgcn_rcpf(1.f + e);
  return copysignf(t, z);
}
__device__ __forceinline__ bf16x8 cvt8(float4 a, float4 b) {
  bf16x8 r;
  r[0] = (__bf16)a.x; r[1] = (__bf16)a.y; r[2] = (__bf16)a.z; r[3] = (__bf16)a.w;
  r[4] = (__bf16)b.x; r[5] = (__bf16)b.y; r[6] = (__bf16)b.z; r[7] = (__bf16)b.w;
  return r;
}

// Pack W_x/W_h fp32 -> bf16 for the 32x32x16 MFMA B-operand, in 12 slot-blocks
// of 16KB. Slot s = cq*3 + p (cq = col-quarter 0..3, p = pair 0..2).
// Pair members (p, mp): (0,0)=Wx_r (0,1)=Wh_r (1,0)=Wh_h (1,1)=Wx_h
//                       (2,0)=Wx_u (2,1)=Wh_u
// 16B chunk t = s*1024 + mp*512 + ks*64 + lane holds
//   W[ro + cq*32 + (lane&31)][ks*16 + (lane>>5)*8 .. +7]
// i.e. B[k][n] fragment: n = lane&31, k = ks*16 + (lane>>5)*8 + j.
// Staged linearly by global_load_lds (wave-uniform base + lane*16); read back
// with wave-linear ds_read_b128 -> 0 bank conflicts.
__global__ void pack_weights_kernel(const float* __restrict__ Wx,
                                    const float* __restrict__ Wh,
                                    unsigned short* __restrict__ wp) {
  int t = blockIdx.x * 256 + threadIdx.x;
  if (t >= 12288) return;          // 12 slots * 1024 chunks
  int s    = t >> 10;
  int rem  = t & 1023;
  int mp   = rem >> 9;
  int ks   = (rem >> 6) & 7;
  int lane = rem & 63;
  int cq   = s / 3;
  int p    = s % 3;
  const float* src; int ro;
  if (p == 0) { src = mp ? Wh : Wx; ro = 128; }        // Wx_r / Wh_r
  else if (p == 1) { src = mp ? Wx : Wh; ro = 256; }   // Wh_h / Wx_h
  else { src = mp ? Wh : Wx; ro = 0; }                 // Wx_u / Wh_u
  const float* q = src + (ro + cq * 32 + (lane & 31)) * 128
                       + ks * 16 + (lane >> 5) * 8;
  *(bf16x8*)(wp + t * 8) = cvt8(*(const float4*)q, *(const float4*)(q + 4));
}

// 256 threads = 4 waves, wave owns 32 rows via 32x32x16 MFMA (block: 128 rows).
// 4 col-quarters x 3 pair-phases; 16KB stages double-buffered in 32KB LDS,
// 1 fence per phase. 512 blocks -> whole grid co-resident (2 blocks/CU).
// Each 16B ds_read B-frag feeds 32768 FLOP (2x the 16x16 ratio) and A-frags
// for 32 rows cost only 64 VGPR -> no spill (tripwire: WRITE_SIZE == output).
__global__ __launch_bounds__(256, 1) void augru_kernel(
    const float* __restrict__ x, const float* __restrict__ hp,
    const float* __restrict__ att, const unsigned short* __restrict__ wp,
    const float* __restrict__ bx, const float* __restrict__ bh,
    float* __restrict__ out) {
  __shared__ __align__(16) unsigned short wlds[2][8192];  // 2 x 16KB
  const int tid   = threadIdx.x;
  const int wave  = tid >> 6;
  const int lane  = tid & 63;
  const int l31   = lane & 31;
  const int khalf = lane >> 5;                    // K-half select (A and B)
  const int rbase = blockIdx.x * 128 + wave * 32; // this wave's 32 rows

  // stage slot s (16KB) into buf s&1: 4 rounds x 256 threads x 16B, linear
  auto stage = [&](int s) {
#pragma unroll
    for (int i = 0; i < 4; ++i) {
      const unsigned short* g = wp + s * 8192 + (i * 256 + tid) * 8;
      unsigned short* l = &wlds[s & 1][(i * 256 + wave * 64) * 8];  // HW adds lane*16B
      __builtin_amdgcn_global_load_lds(
          (const __attribute__((address_space(1))) void*)g,
          (__attribute__((address_space(3))) void*)l, 16, 0, 0);
    }
  };

  stage(0);  // in flight while we build A-fragments

  // A-frags: A[m][k], m = rbase + l31, k = ks*16 + khalf*8 + j. fp32 -> bf16.
  bf16x8 xf[8], hf[8];
  {
    const float* xr = x  + (rbase + l31) * 128 + khalf * 8;
    const float* hr = hp + (rbase + l31) * 128 + khalf * 8;
#pragma unroll
    for (int ks = 0; ks < 8; ++ks) {
      xf[ks] = cvt8(*(const float4*)(xr + ks * 16), *(const float4*)(xr + ks * 16 + 4));
      hf[ks] = cvt8(*(const float4*)(hr + ks * 16), *(const float4*)(hr + ks * 16 + 4));
    }
  }

  // one matrix gemm: 8 ds_read_b128 + 8 MFMA (32x32x16), wave-linear reads
  auto gemm = [&](int b, int mp, const bf16x8 (&af)[8], f32x16 acc) -> f32x16 {
#pragma unroll
    for (int ks = 0; ks < 8; ++ks) {
      bf16x8 bfrag = *(const bf16x8*)&wlds[b][(mp * 512 + ks * 64 + lane) * 8];
      acc = __builtin_amdgcn_mfma_f32_32x32x16_bf16(af[ks], bfrag, acc, 0, 0, 0);
    }
    return acc;
  };
  auto fence = [&]() {
    asm volatile("s_waitcnt vmcnt(0)" ::: "memory");
    __syncthreads();
  };

  fence();  // slot-0 weights + A-frags resident

#pragma unroll 1
  for (int cq = 0; cq < 4; ++cq) {
    const int s0  = cq * 3;
    const int col = cq * 32 + l31;            // this lane's output column
    const float br  = bx[128 + col] + bh[128 + col];
    const float bhh = bh[256 + col];
    const float bxh = bx[256 + col];
    const float bu  = bx[col] + bh[col];

    // --- phase 0: {Wx_r, Wh_r} in buf[s0&1] -> r-gate
    stage(s0 + 1);
    f32x16 accA = (f32x16)0.f;
    accA = gemm(s0 & 1, 0, xf, accA);
    accA = gemm(s0 & 1, 1, hf, accA);
    f32x16 rg;
#pragma unroll
    for (int e = 0; e < 16; ++e) rg[e] = sigmoid_f(accA[e] + br);
    fence();

    // --- phase 1: {Wh_h, Wx_h} in buf[(s0+1)&1] -> h_tilde
    stage(s0 + 2);
    f32x16 accB = (f32x16)0.f;
    accB = gemm((s0 + 1) & 1, 0, hf, accB);   // h . Wh_h
    accA = (f32x16)0.f;
    accA = gemm((s0 + 1) & 1, 1, xf, accA);   // x . Wx_h
#pragma unroll
    for (int e = 0; e < 16; ++e)              // tanh(x.Wxh + bxh + r*(h.Whh + bhh))
      rg[e] = tanh_f(accA[e] + bxh + rg[e] * (accB[e] + bhh));
    fence();

    // --- phase 2: {Wx_u, Wh_u} in buf[s0&1] -> u, blend, store
    if (s0 + 3 < 12) stage(s0 + 3);
    accA = (f32x16)0.f;
    accA = gemm(s0 & 1, 0, xf, accA);
    accA = gemm(s0 & 1, 1, hf, accA);
#pragma unroll
    for (int e = 0; e < 16; ++e) {
      int row = rbase + (e & 3) + 8 * (e >> 2) + 4 * khalf;  // C/D row map (HW-verified)
      float u  = sigmoid_f(accA[e] + bu);
      float ua = att[row] * u;
      float h0 = hp[row * 128 + col];
      out[row * 128 + col] = fmaf(ua, rg[e] - h0, h0);  // (1-ua)*h0 + ua*h_tilde
    }
    if (s0 + 3 < 12) fence();
  }
}

extern "C" void kernel_launch(void* const* d_in, const int* in_sizes, int n_in,
                              void* d_out, int out_size, void* d_ws, size_t ws_size,
                              hipStream_t stream) {
  const float* x   = (const float*)d_in[0];
  const float* hpv = (const float*)d_in[1];
  const float* att = (const float*)d_in[2];
  const float* Wx  = (const float*)d_in[3];
  const float* bx  = (const float*)d_in[4];
  const float* Wh  = (const float*)d_in[5];
  const float* bh  = (const float*)d_in[6];
  float* out = (float*)d_out;
  unsigned short* wp = (unsigned short*)d_ws;  // 196,608 B of scratch

  pack_weights_kernel<<<48, 256, 0, stream>>>(Wx, Wh, wp);
  augru_kernel<<<512, 256, 0, stream>>>(x, hpv, att, wp, bx, bh, out);
}